// Round 6
// baseline (487.348 us; speedup 1.0000x reference)
//
#include <hip/hip_runtime.h>
#include <hip/hip_bf16.h>

typedef float  f32x4  __attribute__((ext_vector_type(4)));
typedef __bf16 bf16x8 __attribute__((ext_vector_type(8)));

#define SCALE_QK 0.17677669529663687f  /* 32^-0.5 (reference uses DIM_HEAD) */

// B=131072, L=4, dim=256, inner=32, heads=4, dh=8
// rows = 524288 ; 16-row tiles = 32768 ; 2-tile PAIRS = 16384
// grid 1024 x 4 waves x 4 pairs = 16384
// JOURNAL: occupancy pinned at 8 waves/CU across r1-r5; all attempts to raise
// it caused VGPR-cap spills (r2:64, r4:84, r5:128-with-spill). Strategy flip:
// spend the 256-VGPR budget (cap at (256,2), r1 proof) on 2-tile-deep MLP.

template<int CTRL>
__device__ __forceinline__ float dpp_add(float x) {
  int xi = __builtin_bit_cast(int, x);
  int yi = __builtin_amdgcn_mov_dpp(xi, CTRL, 0xF, 0xF, true);
  return x + __builtin_bit_cast(float, yi);
}

// ---------- prekernel: pack frag-ordered bf16 weights into d_ws ----------
// item = f*64 + lane, f in [0,64): wsf[item*8 + j]
// f in [0,48): GEMM1 frag (kt=f/6, ct=f%6): col n=ct*16+c, k=kt*32+g*8+j
// f in [48,64): Wo frag ct=f-48: col n=ct*16+c, k=g*8+j
__global__ void pack_weights(const float* __restrict__ Wq, const float* __restrict__ Wkv,
                             const float* __restrict__ Wo, __bf16* __restrict__ wsf) {
  const int item = blockIdx.x * 256 + threadIdx.x;   // 4096 items
  const int f = item >> 6, lane = item & 63;
  const int g = lane >> 4, c = lane & 15;
  union { bf16x8 v; __bf16 h[8]; } vv;
  if (f < 48) {
    const int kt = f / 6, ct = f - kt * 6;
    const int n = ct * 16 + c;
    #pragma unroll
    for (int j = 0; j < 8; ++j) {
      const int k = kt * 32 + g * 8 + j;
      vv.h[j] = (__bf16)((n < 32) ? Wq[k * 32 + n] : Wkv[k * 64 + (n - 32)]);
    }
  } else {
    const int ct = f - 48;
    const int n = ct * 16 + c;
    #pragma unroll
    for (int j = 0; j < 8; ++j) vv.h[j] = (__bf16)Wo[(g * 8 + j) * 256 + n];
  }
  *(bf16x8*)&wsf[item * 8] = vv.v;
}

#define FR(f) (*(const bf16x8*)&wfrag[(f)][lane][0])
#define MFMA(a, b, cc) __builtin_amdgcn_mfma_f32_16x16x32_bf16((a), (b), (cc), 0, 0, 0)

__global__ __launch_bounds__(256, 2) void fused_stattn(
    const float* __restrict__ x, const __bf16* __restrict__ wsf,
    const float* __restrict__ bo, const float* __restrict__ pe,
    float* __restrict__ out) {
  __shared__ __align__(16) __bf16 wfrag[64][64][8];   // 64 KiB (all frags)
  __shared__ __align__(16) __bf16 ao_lds[4][16][40];  // per-wave bounce
  __shared__ __align__(16) float bo_lds[256];
  __shared__ float pe_lds[64];

  const int tid  = threadIdx.x;
  const int lane = tid & 63;
  const int wv   = tid >> 6;
  const int g    = lane >> 4;
  const int c    = lane & 15;

  // prologue: all weight frags ws -> LDS (4096 x 16B chunks)
  #pragma unroll
  for (int it = 0; it < 16; ++it) {
    const int idx = it * 256 + tid;
    *(bf16x8*)&wfrag[0][0][idx * 8] = *(const bf16x8*)&wsf[idx * 8];
  }
  bo_lds[tid] = bo[tid];
  if (tid < 64) pe_lds[tid] = pe[tid];
  __syncthreads();

  const int slot  = blockIdx.x * 4 + wv;  // 0..4095
  const int pair0 = slot * 4;             // 4 pairs (8 tiles) per wave
  const f32x4* xv = (const f32x4*)x;      // row stride = 64 float4s (1 KiB)

  f32x4 xtA[16], xtB[16];
  union uaf { bf16x8 v; __bf16 h[8]; };
  uaf afA[8], afB[8];                     // A-frags: row=c, k=kt*32+g*8+j

  {  // prologue: load + convert pair0 (tiles 2*pair0, 2*pair0+1)
    const int baseA = (pair0 * 32 + c) * 64 + g * 2;
    const int baseB = baseA + 1024;       // +16 rows
    #pragma unroll
    for (int kt = 0; kt < 8; ++kt) {
      xtA[2*kt] = xv[baseA + kt*8];  xtA[2*kt+1] = xv[baseA + kt*8 + 1];
    }
    #pragma unroll
    for (int kt = 0; kt < 8; ++kt) {
      xtB[2*kt] = xv[baseB + kt*8];  xtB[2*kt+1] = xv[baseB + kt*8 + 1];
    }
    #pragma unroll
    for (int kt = 0; kt < 8; ++kt)
      #pragma unroll
      for (int j = 0; j < 4; ++j) {
        afA[kt].h[j]   = (__bf16)xtA[2*kt][j];
        afA[kt].h[4+j] = (__bf16)xtA[2*kt+1][j];
        afB[kt].h[j]   = (__bf16)xtB[2*kt][j];
        afB[kt].h[4+j] = (__bf16)xtB[2*kt+1][j];
      }
  }

  for (int pi = 0; pi < 4; ++pi) {
    const int pair  = pair0 + pi;
    const int npair = (pair + 1 < 16384) ? pair + 1 : pair;  // global clamp
    const int nbaseA = (npair * 32 + c) * 64 + g * 2;

    // ---- GEMM1 both tiles: 8kt x (6 LDS frags shared, 12 MFMA);
    //      interleave next-pair tile-A loads ----
    f32x4 acc[2][6];
    #pragma unroll
    for (int tt = 0; tt < 2; ++tt)
      #pragma unroll
      for (int q = 0; q < 6; ++q) acc[tt][q] = (f32x4){0,0,0,0};

    #pragma unroll
    for (int kt = 0; kt < 8; ++kt) {
      const bf16x8 w0 = FR(kt*6+0), w1 = FR(kt*6+1), w2 = FR(kt*6+2);
      const bf16x8 w3 = FR(kt*6+3), w4 = FR(kt*6+4), w5 = FR(kt*6+5);
      acc[0][0] = MFMA(afA[kt].v, w0, acc[0][0]);
      acc[0][1] = MFMA(afA[kt].v, w1, acc[0][1]);
      acc[0][2] = MFMA(afA[kt].v, w2, acc[0][2]);
      acc[0][3] = MFMA(afA[kt].v, w3, acc[0][3]);
      acc[0][4] = MFMA(afA[kt].v, w4, acc[0][4]);
      acc[0][5] = MFMA(afA[kt].v, w5, acc[0][5]);
      acc[1][0] = MFMA(afB[kt].v, w0, acc[1][0]);
      acc[1][1] = MFMA(afB[kt].v, w1, acc[1][1]);
      acc[1][2] = MFMA(afB[kt].v, w2, acc[1][2]);
      acc[1][3] = MFMA(afB[kt].v, w3, acc[1][3]);
      acc[1][4] = MFMA(afB[kt].v, w4, acc[1][4]);
      acc[1][5] = MFMA(afB[kt].v, w5, acc[1][5]);
      // next-pair tile-A k-slab (afA[kt] just had its last use)
      xtA[2*kt]   = xv[nbaseA + kt*8];
      xtA[2*kt+1] = xv[nbaseA + kt*8 + 1];
    }
    // C layout: lane(g,c) reg i -> row g*4+i (batch g, seq i), col c.

    const int h0 = c >> 3;
    #pragma unroll
    for (int tt = 0; tt < 2; ++tt) {
      const int tile = pair * 2 + tt;

      // ---- attention (in registers; 8-lane head-dim reduce via DPP) ----
      float ao0[4], ao1[4];
      #pragma unroll
      for (int p = 0; p < 2; ++p) {
        const f32x4 qa = acc[tt][p];
        const f32x4 ka = acc[tt][2 + p];
        const f32x4 va = acc[tt][4 + p];
        const int ph = 2 * p + h0;
        float sim[4][4];
        #pragma unroll
        for (int i = 0; i < 4; ++i)
          #pragma unroll
          for (int j = 0; j < 4; ++j) {
            float pr = qa[i] * ka[j];
            pr = dpp_add<0xB1>(pr);             // quad_perm xor1
            pr = dpp_add<0x4E>(pr);             // quad_perm xor2
            pr = dpp_add<0x141>(pr);            // row_half_mirror
            sim[i][j] = pr * SCALE_QK + pe_lds[ph * 16 + i * 4 + j];
          }
        #pragma unroll
        for (int i = 0; i < 4; ++i) {
          const float m = fmaxf(fmaxf(sim[i][0], sim[i][1]), fmaxf(sim[i][2], sim[i][3]));
          const float e0 = __expf(sim[i][0] - m), e1 = __expf(sim[i][1] - m);
          const float e2 = __expf(sim[i][2] - m), e3 = __expf(sim[i][3] - m);
          const float rs = 1.0f / (e0 + e1 + e2 + e3);
          const float o  = (e0*va[0] + e1*va[1] + e2*va[2] + e3*va[3]) * rs;
          if (p) ao1[i] = o; else ao0[i] = o;
        }
      }

      // ---- bounce C-layout -> B-frag layout (per-wave private) ----
      #pragma unroll
      for (int i = 0; i < 4; ++i) {
        ao_lds[wv][g*4 + i][c]      = (__bf16)ao0[i];
        ao_lds[wv][g*4 + i][16 + c] = (__bf16)ao1[i];
      }
      const bf16x8 a2 = *(const bf16x8*)&ao_lds[wv][c][g * 8];

      // ---- GEMM2 (swapped): Wo^T @ ao^T, bias as C-input, float4 stores ----
      const int orow = (tile * 16 + c) * 256;
      #pragma unroll
      for (int ct = 0; ct < 16; ++ct) {
        const f32x4 bv = *(const f32x4*)&bo_lds[ct * 16 + g * 4];
        f32x4 o = MFMA(FR(48 + ct), a2, bv);
        *(f32x4*)&out[orow + ct * 16 + g * 4] = o;
      }

      // ---- after tile A completes: issue next-pair tile-B loads ----
      if (tt == 0) {
        const int nbaseB = nbaseA + 1024;
        #pragma unroll
        for (int kt = 0; kt < 8; ++kt) {
          xtB[2*kt]   = xv[nbaseB + kt*8];
          xtB[2*kt+1] = xv[nbaseB + kt*8 + 1];
        }
      }
    }

    // ---- wait + convert next pair's x to bf16 frags (f32 temps die) ----
    #pragma unroll
    for (int kt = 0; kt < 8; ++kt)
      #pragma unroll
      for (int j = 0; j < 4; ++j) {
        afA[kt].h[j]   = (__bf16)xtA[2*kt][j];
        afA[kt].h[4+j] = (__bf16)xtA[2*kt+1][j];
        afB[kt].h[j]   = (__bf16)xtB[2*kt][j];
        afB[kt].h[4+j] = (__bf16)xtB[2*kt+1][j];
      }
  }
}

extern "C" void kernel_launch(void* const* d_in, const int* in_sizes, int n_in,
                              void* d_out, int out_size, void* d_ws, size_t ws_size,
                              hipStream_t stream) {
  const float* x   = (const float*)d_in[0];
  const float* Wq  = (const float*)d_in[1];
  const float* Wkv = (const float*)d_in[2];
  const float* Wo  = (const float*)d_in[3];
  const float* bo  = (const float*)d_in[4];
  const float* pe  = (const float*)d_in[5];
  float* out = (float*)d_out;
  __bf16* wsf = (__bf16*)d_ws;   // 64 KiB of frag-ordered bf16 weights

  hipLaunchKernelGGL(pack_weights, dim3(16), dim3(256), 0, stream, Wq, Wkv, Wo, wsf);
  hipLaunchKernelGGL(fused_stattn, dim3(1024), dim3(256), 0, stream,
                     x, wsf, bo, pe, out);
}

// Round 7
// 375.144 us; speedup vs baseline: 1.2991x; 1.2991x over previous
//
#include <hip/hip_runtime.h>
#include <hip/hip_bf16.h>

typedef float  f32x4  __attribute__((ext_vector_type(4)));
typedef __bf16 bf16x8 __attribute__((ext_vector_type(8)));

#define SCALE_QK 0.17677669529663687f  /* 32^-0.5 (reference uses DIM_HEAD) */

// B=131072, L=4, dim=256, inner=32, heads=4, dh=8
// rows = 524288 ; 16-row tiles = 32768 ; grid 1024 x 4 waves x 8 tiles
// JOURNAL: allocator pins this kernel at <=128 VGPR (r1..r6); register-based
// prefetch either sinks (latency exposed) or spills. This round: x staged
// HBM->LDS via global_load_lds (no VGPR dest) + counted vmcnt(16) per tile
// (m97/m201 recipe). Weights stay in global (L1-hit). 139.5KB dyn LDS,
// 1 block/CU, 4 waves/CU, BW-bound by construction.

template<int CTRL>
__device__ __forceinline__ float dpp_add(float x) {
  int xi = __builtin_bit_cast(int, x);
  int yi = __builtin_amdgcn_mov_dpp(xi, CTRL, 0xF, 0xF, true);
  return x + __builtin_bit_cast(float, yi);
}

// ---------- prekernel: pack frag-ordered bf16 weights into d_ws ----------
// item = f*64 + lane, f in [0,64): wsf[item*8 + j]
// f in [0,48): GEMM1 frag (kt=f/6, ct=f%6): col n=ct*16+c, k=kt*32+g*8+j
// f in [48,64): Wo frag ct=f-48: col n=ct*16+c, k=g*8+j
__global__ void pack_weights(const float* __restrict__ Wq, const float* __restrict__ Wkv,
                             const float* __restrict__ Wo, __bf16* __restrict__ wsf) {
  const int item = blockIdx.x * 256 + threadIdx.x;   // 4096 items
  const int f = item >> 6, lane = item & 63;
  const int g = lane >> 4, c = lane & 15;
  union { bf16x8 v; __bf16 h[8]; } vv;
  if (f < 48) {
    const int kt = f / 6, ct = f - kt * 6;
    const int n = ct * 16 + c;
    #pragma unroll
    for (int j = 0; j < 8; ++j) {
      const int k = kt * 32 + g * 8 + j;
      vv.h[j] = (__bf16)((n < 32) ? Wq[k * 32 + n] : Wkv[k * 64 + (n - 32)]);
    }
  } else {
    const int ct = f - 48;
    const int n = ct * 16 + c;
    #pragma unroll
    for (int j = 0; j < 8; ++j) vv.h[j] = (__bf16)Wo[(g * 8 + j) * 256 + n];
  }
  *(bf16x8*)&wsf[item * 8] = vv.v;
}

#define VMW16() asm volatile("s_waitcnt vmcnt(16)" ::: "memory")
#define FENCE() asm volatile("" ::: "memory")
#define SB0()   __builtin_amdgcn_sched_barrier(0)
#define MFMA(a, b, cc) __builtin_amdgcn_mfma_f32_16x16x32_bf16((a), (b), (cc), 0, 0, 0)

// LDS map (bytes):
//   [0, 133120)      x staging: wave wv, buffer b: wv*33280 + b*16640; row r at +r*1040
//   [133120, 138240) ao bounce: wave wv at +wv*1280 ([16][40] bf16)
//   [138240, 139264) bo (256 f32)
//   [139264, 139520) pe (64 f32)
#define LDS_TOTAL 139520

__global__ __launch_bounds__(256) void fused_stattn(
    const float* __restrict__ x, const __bf16* __restrict__ wsf,
    const float* __restrict__ bo, const float* __restrict__ pe,
    float* __restrict__ out) {
  extern __shared__ char smem[];

  const int tid  = threadIdx.x;
  const int lane = tid & 63;
  const int wv   = tid >> 6;
  const int g    = lane >> 4;
  const int c    = lane & 15;

  float*  bo_l = (float*)(smem + 138240);
  float*  pe_l = (float*)(smem + 139264);
  __bf16* aoW  = (__bf16*)(smem + 133120 + wv * 1280);

  bo_l[tid] = bo[tid];
  if (tid < 64) pe_l[tid] = pe[tid];
  __syncthreads();

  const bf16x8* wq = (const bf16x8*)wsf;     // frag f at wq[f*64 + lane]

  const unsigned smem_lds = (unsigned)(unsigned long long)(void*)smem;  // LDS byte addr
  const unsigned xw_base  = smem_lds + (unsigned)(wv * 33280);

  const int slot  = blockIdx.x * 4 + wv;     // 0..4095
  const int tile0 = slot * 8;

  // stage one 16x256 f32 tile: 16 instrs, each = 64 lanes x 16B = one row
  auto stage_tile = [&](unsigned dbase, int tile) {
    const float* src = x + (size_t)tile * 4096 + (lane << 2);
    #pragma unroll
    for (int r = 0; r < 16; ++r) {
      __builtin_amdgcn_global_load_lds(
          (const __attribute__((address_space(1))) void*)(src + r * 256),
          (__attribute__((address_space(3))) void*)(unsigned long long)(dbase + r * 1040),
          16, 0, 0);
    }
  };

  stage_tile(xw_base, tile0);                // prologue: tile0 -> buf0

  for (int t = 0; t < 8; ++t) {
    const int tile = tile0 + t;
    if (t < 7) {                             // stage t+1 into other buffer
      FENCE();
      stage_tile(xw_base + (unsigned)(((t + 1) & 1) * 16640), tile + 1);
    }
    VMW16();                                 // wait: current tile staged (16 newest stay in flight)
    SB0();

    // ---- GEMM1: x[16x256] @ Wqkv[256x96]; A from LDS, B frags from L1/L2 ----
    const float* xrow = (const float*)(smem + wv * 33280 + (t & 1) * 16640) + c * 260;
    f32x4 acc0 = {0,0,0,0}, acc1 = {0,0,0,0}, acc2 = {0,0,0,0};
    f32x4 acc3 = {0,0,0,0}, acc4 = {0,0,0,0}, acc5 = {0,0,0,0};
    #pragma unroll
    for (int kt = 0; kt < 8; ++kt) {
      const bf16x8 w0 = wq[(kt*6+0)*64 + lane];
      const bf16x8 w1 = wq[(kt*6+1)*64 + lane];
      const bf16x8 w2 = wq[(kt*6+2)*64 + lane];
      const bf16x8 w3 = wq[(kt*6+3)*64 + lane];
      const bf16x8 w4 = wq[(kt*6+4)*64 + lane];
      const bf16x8 w5 = wq[(kt*6+5)*64 + lane];
      const f32x4 va = *(const f32x4*)(xrow + kt * 32 + g * 8);
      const f32x4 vb = *(const f32x4*)(xrow + kt * 32 + g * 8 + 4);
      union { bf16x8 v; __bf16 h[8]; } af;   // A-frag: row=c, k=kt*32+g*8+j
      #pragma unroll
      for (int j = 0; j < 4; ++j) { af.h[j] = (__bf16)va[j]; af.h[4+j] = (__bf16)vb[j]; }
      acc0 = MFMA(af.v, w0, acc0);
      acc1 = MFMA(af.v, w1, acc1);
      acc2 = MFMA(af.v, w2, acc2);
      acc3 = MFMA(af.v, w3, acc3);
      acc4 = MFMA(af.v, w4, acc4);
      acc5 = MFMA(af.v, w5, acc5);
    }
    // C layout: lane(g,c) reg i -> row g*4+i (batch g, seq i), col c.

    // ---- attention (in registers; 8-lane head-dim reduce via DPP) ----
    const int h0 = c >> 3;
    float ao0[4], ao1[4];
    #pragma unroll
    for (int p = 0; p < 2; ++p) {
      const f32x4 qa = p ? acc1 : acc0;
      const f32x4 ka = p ? acc3 : acc2;
      const f32x4 va = p ? acc5 : acc4;
      const int ph = 2 * p + h0;
      float sim[4][4];
      #pragma unroll
      for (int i = 0; i < 4; ++i)
        #pragma unroll
        for (int j = 0; j < 4; ++j) {
          float pr = qa[i] * ka[j];
          pr = dpp_add<0xB1>(pr);             // quad_perm xor1
          pr = dpp_add<0x4E>(pr);             // quad_perm xor2
          pr = dpp_add<0x141>(pr);            // row_half_mirror
          sim[i][j] = pr * SCALE_QK + pe_l[ph * 16 + i * 4 + j];
        }
      #pragma unroll
      for (int i = 0; i < 4; ++i) {
        const float m = fmaxf(fmaxf(sim[i][0], sim[i][1]), fmaxf(sim[i][2], sim[i][3]));
        const float e0 = __expf(sim[i][0] - m), e1 = __expf(sim[i][1] - m);
        const float e2 = __expf(sim[i][2] - m), e3 = __expf(sim[i][3] - m);
        const float rs = 1.0f / (e0 + e1 + e2 + e3);
        const float o  = (e0*va[0] + e1*va[1] + e2*va[2] + e3*va[3]) * rs;
        if (p) ao1[i] = o; else ao0[i] = o;
      }
    }

    // ---- bounce C-layout -> B-frag layout (per-wave private) ----
    #pragma unroll
    for (int i = 0; i < 4; ++i) {
      aoW[(g*4 + i) * 40 + c]      = (__bf16)ao0[i];
      aoW[(g*4 + i) * 40 + 16 + c] = (__bf16)ao1[i];
    }
    const bf16x8 a2 = *(const bf16x8*)&aoW[c * 40 + g * 8];  // col=c(=x-row), k=g*8+j

    // ---- GEMM2 (swapped): Wo^T @ ao^T, bias as C-input, float4 stores ----
    const int orow = (tile * 16 + c) * 256;
    #pragma unroll
    for (int ct = 0; ct < 16; ++ct) {
      const f32x4 bv = *(const f32x4*)&bo_l[ct * 16 + g * 4];
      f32x4 o = MFMA(wq[(48 + ct) * 64 + lane], a2, bv);
      *(f32x4*)&out[orow + ct * 16 + g * 4] = o;
    }
  }
}

extern "C" void kernel_launch(void* const* d_in, const int* in_sizes, int n_in,
                              void* d_out, int out_size, void* d_ws, size_t ws_size,
                              hipStream_t stream) {
  const float* x   = (const float*)d_in[0];
  const float* Wq  = (const float*)d_in[1];
  const float* Wkv = (const float*)d_in[2];
  const float* Wo  = (const float*)d_in[3];
  const float* bo  = (const float*)d_in[4];
  const float* pe  = (const float*)d_in[5];
  float* out = (float*)d_out;
  __bf16* wsf = (__bf16*)d_ws;   // 64 KiB of frag-ordered bf16 weights

  (void)hipFuncSetAttribute(reinterpret_cast<const void*>(fused_stattn),
                            hipFuncAttributeMaxDynamicSharedMemorySize, LDS_TOTAL);
  hipLaunchKernelGGL(pack_weights, dim3(16), dim3(256), 0, stream, Wq, Wkv, Wo, wsf);
  hipLaunchKernelGGL(fused_stattn, dim3(1024), dim3(256), LDS_TOTAL, stream,
                     x, wsf, bo, pe, out);
}